// Round 5
// baseline (146.741 us; speedup 1.0000x reference)
//
#include <hip/hip_runtime.h>
#include <hip/hip_bf16.h>

// MoE fused block, MI355X gfx950.
// Shapes: B=2, C=256, T*H*W=16384, E=4, K=2. All inputs fp32, output fp32.
//
// R10 -> R11:
//  * Wave grid reshaped (nv8 x mh2) -> (nv4 x mh4): each wave owns 64 output
//    channels x 32 M-rows. A-fragment LDS reads (shared by all waves of an
//    nv-group) halve: redundancy 8 -> 4, MFMA:ds_read goes 2:1 -> 4:1.
//    GEMM1's conflict-heavy gathered-row reads halve; GEMM2's rows are
//    16-consecutive (bank-quad free). Registers: bw/cw ring-2 x 4 frags =
//    32 VGPR; hacc[<=2][4] + oacc[2][4] = 64 AGPR. Same 128/wave envelope.
//  * GEMM1 tiles round-robin over mh (tile j done by wave mh = j%4);
//    per-wave template dispatch keeps exactly one barrier per wave per phase.
//  * Staging / gate / ballot / zero-fill / direct-store epilogue unchanged
//    (staging keeps its own 8x32-channel wave mapping).

#define C_DIM 256
#define S_DIM 16384          // T*H*W
#define E_DIM 4
#define MT 128               // positions per workgroup
#define XST 264              // Xs/Hs row stride in shorts (16B-aligned rows)
#define WFRAG_ELEMS 262144   // elements per prepacked weight tensor (4*16*8*64*8)

typedef __attribute__((ext_vector_type(8))) short bf16x8;
typedef __attribute__((ext_vector_type(4))) float f32x4;

__device__ __forceinline__ short bfq(float f) {
  __hip_bfloat16 h = __float2bfloat16(f);
  return *(short*)&h;
}

// Prepack: dst[(half,e,nt,kc,lane,j)] = src[(e*256 + nt*16 + (lane&15))*256
//                                           + kc*32 + (lane>>4)*8 + j]
// B-operand fragment layout for mfma_f32_16x16x32_bf16: n=lane&15, k=(lane>>4)*8+j.
// 32 consecutive threads read one contiguous 1KB source row (fully coalesced);
// the 16B fragment stores scatter (fire-and-forget).
__global__ __launch_bounds__(256) void prepack_kernel(
    const float* __restrict__ w1, const float* __restrict__ w2,
    __hip_bfloat16* __restrict__ dst)
{
  int o8   = blockIdx.x * 256 + threadIdx.x;  // 0 .. 65535 (8-elem chunks)
  int half = o8 >> 15;                        // 0: w1, 1: w2
  int idx  = o8 & 32767;
  int j    = idx & 31;                        // 8-float chunk within source row
  int rowid= idx >> 5;                        // e*256 + nt*16 + row, 0..1023
  int e    = rowid >> 8;
  int nt   = (rowid >> 4) & 15;
  int row  = rowid & 15;
  int kc   = j >> 2;
  int col8 = j & 3;
  int lane = (col8 << 4) | row;
  const float* src = half ? w2 : w1;
  const float* s = src + rowid * 256 + j * 8;
  const float4 v0 = *(const float4*)s;
  const float4 v1 = *(const float4*)(s + 4);
  bf16x8 outv = {bfq(v0.x), bfq(v0.y), bfq(v0.z), bfq(v0.w),
                 bfq(v1.x), bfq(v1.y), bfq(v1.z), bfq(v1.w)};
  int chunk = ((e*16 + nt)*8 + kc)*64 + lane;
  *(bf16x8*)((short*)dst + half*WFRAG_ELEMS + chunk*8) = outv;
}

// GEMM1 over TW gathered M-tiles (tile j = mh + 4*i, round-robin over mh).
// Barrier (protecting Hs readers of the previous expert's GEMM2) sits BETWEEN
// the MFMA loop and the H-scatter. Ring-2 weight prefetch, 4 B-frags (N=64).
template<int TW>
__device__ __forceinline__ void gemm1_sparse(
    const short* XsS, short* HsS, const short* w1e, const float* b1e,
    const unsigned char* plist_e, const float* wgtg_e,
    int mh, int nv, int r, int q, bool dosync)
{
  f32x4 hacc[TW][4];
#pragma unroll
  for (int i = 0; i < TW; ++i)
#pragma unroll
    for (int t = 0; t < 4; ++t) hacc[i][t] = (f32x4){0.f, 0.f, 0.f, 0.f};

  int aoff[TW];
#pragma unroll
  for (int i = 0; i < TW; ++i)
    aoff[i] = (int)plist_e[(mh + 4*i)*16 + r] * XST;

  bf16x8 bw[2][4];
#pragma unroll
  for (int t = 0; t < 4; ++t) bw[0][t] = *(const bf16x8*)(w1e + (t*8 + 0)*512);
#pragma unroll
  for (int kc = 0; kc < 8; ++kc) {
    if (kc < 7) {
#pragma unroll
      for (int t = 0; t < 4; ++t)
        bw[(kc+1)&1][t] = *(const bf16x8*)(w1e + (t*8 + kc + 1)*512);
    }
    bf16x8 a[TW];
#pragma unroll
    for (int i = 0; i < TW; ++i)
      a[i] = *(const bf16x8*)(XsS + aoff[i] + kc*32 + q*8);
#pragma unroll
    for (int i = 0; i < TW; ++i)
#pragma unroll
      for (int t = 0; t < 4; ++t)
        hacc[i][t] = __builtin_amdgcn_mfma_f32_16x16x32_bf16(a[i], bw[kc&1][t], hacc[i][t], 0, 0, 0);
  }

  if (dosync) __syncthreads();   // prev expert's GEMM2 done reading Hs

  // epilogue: +b1, fast SiLU, scale by gathered gate weight, scatter to Hs
#pragma unroll
  for (int i = 0; i < TW; ++i) {
    const int g0 = (mh + 4*i)*16 + q*4;
    const unsigned pw = *(const unsigned*)(plist_e + g0);   // 4 packed positions
    const f32x4 wg = *(const f32x4*)(wgtg_e + g0);
#pragma unroll
    for (int t = 0; t < 4; ++t) {
      const int n = nv*64 + t*16 + r;
      const float bias = b1e[n];
#pragma unroll
      for (int reg = 0; reg < 4; ++reg) {
        const int p = (pw >> (8*reg)) & 255;
        const float z = hacc[i][t][reg] + bias;
        const float s = __builtin_amdgcn_rcpf(1.0f + __expf(-z));
        HsS[p*XST + n] = bfq(z * s * wg[reg]);
      }
    }
  }
}

__global__ __launch_bounds__(1024, 4) void moe_fused_kernel(
    const float* __restrict__ x,
    const float* __restrict__ gate_w,
    const float* __restrict__ gate_b,
    const float* __restrict__ b1,
    const float* __restrict__ b2,
    const __hip_bfloat16* __restrict__ wp,   // [W1P | W2P] prepacked bf16
    float* __restrict__ out)
{
  // pool (135168 B): Xs (67584) + Hs (67584).
  // Gate fp64 partials (32KB) alias the Hs region before its first use.
  __shared__ __align__(16) char pool[2 * MT * XST * 2];
  __shared__ __align__(16) float Wgt[MT * 4];
  __shared__ __align__(16) unsigned char plist[4][192];  // gathered + pad positions
  __shared__ __align__(16) float WgtG[4][192];           // gathered gate weights
  __shared__ __align__(4)  unsigned char zlist[4][128];  // complement positions
  __shared__ int mcnt[4];

  short* XsS = (short*)pool;
  short* HsS = (short*)(pool + MT * XST * 2);

  const int tid  = threadIdx.x;
  const int lane = tid & 63;
  const int wv   = tid >> 6;     // wave 0..15
  const int nv   = wv & 3;       // n-slice owner: channels [nv*64, nv*64+64)
  const int mh   = wv >> 2;      // M-quarter: GEMM2 rows [mh*32, mh*32+32)
  const int r    = lane & 15;
  const int q    = lane >> 4;

  const int g  = blockIdx.x;
  const int b  = g >> 7;                 // 128 workgroups per batch
  const int s0 = (g & 127) * MT;
  const float* xb = x + (size_t)b * C_DIM * S_DIM + s0;

  const short* W1P = (const short*)wp;
  const short* W2P = (const short*)wp + WFRAG_ELEMS;

  // ---- FUSED stage X + gate partials (staging wave map: 8 ch-slices x 2
  //      pos-halves, independent of the GEMM wave map). lane = position.
  //      32 coalesced scalar loads; fp64 gate dot from the regs holding x. ----
  {
    const int sc = wv & 7;          // channel slice
    const int sh = wv >> 3;         // position half
    const int p  = sh*64 + lane;
    const int c0 = sc * 32;
    float xv[32];
#pragma unroll
    for (int j = 0; j < 32; ++j)
      xv[j] = xb[(size_t)(c0 + j) * S_DIM + p];

    double acc[4] = {0.0, 0.0, 0.0, 0.0};
#pragma unroll
    for (int j = 0; j < 32; ++j) {
      const double xd = (double)xv[j];
      acc[0] += xd * (double)gate_w[0*256 + c0 + j];
      acc[1] += xd * (double)gate_w[1*256 + c0 + j];
      acc[2] += xd * (double)gate_w[2*256 + c0 + j];
      acc[3] += xd * (double)gate_w[3*256 + c0 + j];
    }

#pragma unroll
    for (int k = 0; k < 4; ++k) {
      bf16x8 blk = {bfq(xv[k*8+0]), bfq(xv[k*8+1]), bfq(xv[k*8+2]), bfq(xv[k*8+3]),
                    bfq(xv[k*8+4]), bfq(xv[k*8+5]), bfq(xv[k*8+6]), bfq(xv[k*8+7])};
      *(bf16x8*)(XsS + p*XST + c0 + k*8) = blk;
    }

    double* GateD = (double*)HsS;   // 4e x 8grp x 128pos fp64 = 32KB (alias)
#pragma unroll
    for (int e = 0; e < 4; ++e)
      GateD[(e*8 + sc)*128 + p] = acc[e];
  }
  __syncthreads();   // Xs staged AND gate partials written

  // ---- logits (fp64 reduce, fixed order) + top-2 + softmax, fused via shfl ----
  if (tid < 512) {
    const int p = tid >> 2;        // 0..127
    const int e = tid & 3;
    const double* GateD = (const double*)HsS;
    double s = (double)gate_b[e];
#pragma unroll
    for (int g2 = 0; g2 < 8; ++g2) s += GateD[(e*8 + g2)*128 + p];
    const float la = (float)s;              // l[e]
    const float lb = __shfl_xor(la, 1, 64); // l[e^1]
    const float lc = __shfl_xor(la, 2, 64); // l[e^2]
    const float ld = __shfl_xor(lb, 2, 64); // l[e^3]
    if (e == 0) {
      const float l0 = la, l1 = lb, l2 = lc, l3 = ld;
      int i1 = 0; float v1 = l0;
      if (l1 > v1) { v1 = l1; i1 = 1; }
      if (l2 > v1) { v1 = l2; i1 = 2; }
      if (l3 > v1) { v1 = l3; i1 = 3; }
      float v2 = -3.0e38f; int i2 = 0;
      if (i1 != 0 && l0 > v2) { v2 = l0; i2 = 0; }
      if (i1 != 1 && l1 > v2) { v2 = l1; i2 = 1; }
      if (i1 != 2 && l2 > v2) { v2 = l2; i2 = 2; }
      if (i1 != 3 && l3 > v2) { v2 = l3; i2 = 3; }
      const float wA = 1.0f / (1.0f + __expf(v2 - v1));
      const float wB = 1.0f - wA;
      f32x4 w;
      w[0] = (i1 == 0) ? wA : ((i2 == 0) ? wB : 0.0f);
      w[1] = (i1 == 1) ? wA : ((i2 == 1) ? wB : 0.0f);
      w[2] = (i1 == 2) ? wA : ((i2 == 2) ? wB : 0.0f);
      w[3] = (i1 == 3) ? wA : ((i2 == 3) ? wB : 0.0f);
      *(f32x4*)(&Wgt[p*4]) = w;
    }
  }
  __syncthreads();   // Wgt final

  // ---- per-expert gather lists: wave e, two sequential 64-pos ballots ----
  if (wv < 4) {
    const int e = wv;
    int base = 0, zbase = 0;
#pragma unroll
    for (int half = 0; half < 2; ++half) {
      const int p = half*64 + lane;
      const float w = Wgt[p*4 + e];
      const bool sel = (w != 0.0f);
      const unsigned long long mask = __ballot(sel);
      const int below = __popcll(mask & ((1ull << lane) - 1ull));
      const int m = __popcll(mask);
      if (sel) {
        plist[e][base + below] = (unsigned char)p;
        WgtG[e][base + below]  = w;
      } else {
        zlist[e][zbase + lane - below] = (unsigned char)p;
      }
      base += m; zbase += 64 - m;
    }
    const int me  = base;
    const int mt2 = (me + 15) >> 4;          // 16-row tiles total
    const int pad = mt2*16 - me;             // <= 15, and <= 128-me
    if (lane < pad) {                        // weight-0 complement padding rows
      plist[e][me + lane] = zlist[e][lane];
      WgtG[e][me + lane]  = 0.0f;
    }
    if (lane == 0) mcnt[e] = me;
  }
  __syncthreads();   // lists final (GateD fully consumed before H-scatter)

  f32x4 oacc[2][4];   // [Mtq][t]: persistent out accumulator, K=1024 concat
#pragma unroll
  for (int i = 0; i < 2; ++i)
#pragma unroll
    for (int t = 0; t < 4; ++t) oacc[i][t] = (f32x4){0.f, 0.f, 0.f, 0.f};

  for (int e = 0; e < E_DIM; ++e) {
    const int me  = mcnt[e];   // WG-uniform
    const int mt2 = __builtin_amdgcn_readfirstlane((me + 15) >> 4);   // 0..8
    const short* w1e = W1P + ((e*16 + nv*4)*8)*512 + lane*8;
    const float* b1e = b1 + e*256;
    const bool dosync = (e > 0);   // wait for prev GEMM2's Hs readers
    const int tw = (mt2 > mh) ? ((mt2 - mh + 3) >> 2) : 0;  // this wave's tiles

    if      (tw == 1) gemm1_sparse<1>(XsS, HsS, w1e, b1e, plist[e], WgtG[e], mh, nv, r, q, dosync);
    else if (tw == 2) gemm1_sparse<2>(XsS, HsS, w1e, b1e, plist[e], WgtG[e], mh, nv, r, q, dosync);
    else { if (dosync) __syncthreads(); }   // tw==0: still must sync

    // GEMM2 prologue: first kc B-fragments, issued before zero-fill + barrier
    const short* w2e = W2P + ((e*16 + nv*4)*8)*512 + lane*8;
    bf16x8 cw[2][4];
#pragma unroll
    for (int t = 0; t < 4; ++t) cw[0][t] = *(const bf16x8*)(w2e + (t*8 + 0)*512);

    // zero-fill complement rows of Hs (positions not using expert e)
    {
      const int zm = MT - me;
      const bf16x8 zz = {0,0,0,0,0,0,0,0};
      for (int i = tid; i < zm*32; i += 1024) {
        const int row = zlist[e][i >> 5];
        *(bf16x8*)(HsS + row*XST + (i & 31)*8) = zz;
      }
    }
    __syncthreads();   // Hs complete (gathered writes + zero fill)

    // ---- GEMM2: oacc += H_e(128x256) @ W2_e^T slice; this wave: rows
    //      [mh*32, mh*32+32) x channels [nv*64, nv*64+64) ----
    {
#pragma unroll
      for (int kc = 0; kc < 8; ++kc) {
        if (kc < 7) {
#pragma unroll
          for (int t = 0; t < 4; ++t)
            cw[(kc+1)&1][t] = *(const bf16x8*)(w2e + (t*8 + kc + 1)*512);
        }
        bf16x8 a[2];
#pragma unroll
        for (int Mtq = 0; Mtq < 2; ++Mtq)
          a[Mtq] = *(const bf16x8*)(HsS + (mh*32 + Mtq*16 + r)*XST + kc*32 + q*8);
#pragma unroll
        for (int Mtq = 0; Mtq < 2; ++Mtq)
#pragma unroll
          for (int t = 0; t < 4; ++t)
            oacc[Mtq][t] = __builtin_amdgcn_mfma_f32_16x16x32_bf16(a[Mtq], cw[kc&1][t], oacc[Mtq][t], 0, 0, 0);
      }
    }
    // no barrier here: next expert's GEMM1 compute doesn't touch Hs; the
    // barrier protecting Hs sits inside gemm1_sparse, before its scatter.
  }

  // ---- O epilogue: direct stores. Lane holds 4 CONSECUTIVE positions per
  //      fragment (D-layout row = q*4+reg), so float4 res/store per (Mtq,t).
  //      Reads Wgt (stable LDS) + registers only: no barrier needed. ----
  {
    float b2v[4][4];   // [t][e] for c = nv*64 + t*16 + r
#pragma unroll
    for (int t = 0; t < 4; ++t) {
      const int c = nv*64 + t*16 + r;
#pragma unroll
      for (int e = 0; e < 4; ++e) b2v[t][e] = b2[e*256 + c];
    }
    float* ob = out + (size_t)b * C_DIM * S_DIM + s0;
#pragma unroll
    for (int Mtq = 0; Mtq < 2; ++Mtq) {
      const int pb = mh*32 + Mtq*16 + q*4;
      f32x4 wv4[4];
#pragma unroll
      for (int reg = 0; reg < 4; ++reg)
        wv4[reg] = *(const f32x4*)(&Wgt[(pb + reg)*4]);
#pragma unroll
      for (int t = 0; t < 4; ++t) {
        const int c = nv*64 + t*16 + r;
        f32x4 v = oacc[Mtq][t];
#pragma unroll
        for (int reg = 0; reg < 4; ++reg)
          v[reg] += wv4[reg][0]*b2v[t][0] + wv4[reg][1]*b2v[t][1]
                  + wv4[reg][2]*b2v[t][2] + wv4[reg][3]*b2v[t][3];
        const float4 xr = *(const float4*)(xb + (size_t)c*S_DIM + pb);
        float4 res;
        res.x = v[0] + xr.x; res.y = v[1] + xr.y;
        res.z = v[2] + xr.z; res.w = v[3] + xr.w;
        *(float4*)(ob + (size_t)c*S_DIM + pb) = res;
      }
    }
  }
}

extern "C" void kernel_launch(void* const* d_in, const int* in_sizes, int n_in,
                              void* d_out, int out_size, void* d_ws, size_t ws_size,
                              hipStream_t stream)
{
  (void)in_sizes; (void)n_in; (void)out_size; (void)ws_size;
  const float* x      = (const float*)d_in[0];
  const float* gate_w = (const float*)d_in[1];
  const float* gate_b = (const float*)d_in[2];
  const float* w1     = (const float*)d_in[3];
  const float* b1     = (const float*)d_in[4];
  const float* w2     = (const float*)d_in[5];
  const float* b2     = (const float*)d_in[6];
  float* out = (float*)d_out;
  __hip_bfloat16* wpack = (__hip_bfloat16*)d_ws;   // needs 1 MiB of scratch

  prepack_kernel<<<256, 256, 0, stream>>>(w1, w2, wpack);
  moe_fused_kernel<<<256, 1024, 0, stream>>>(x, gate_w, gate_b, b1, b2, wpack, out);
}

// Round 7
// 128.658 us; speedup vs baseline: 1.1406x; 1.1406x over previous
//
#include <hip/hip_runtime.h>
#include <hip/hip_bf16.h>

// MoE fused block, MI355X gfx950.
// Shapes: B=2, C=256, T*H*W=16384, E=4, K=2. All inputs fp32, output fp32.
//
// R12 resubmit (round-6 run died to the same container/infra failure seen in
// round 3, which passed cleanly on unchanged resubmit in round 4; audit found
// no defect — barriers WG-uniform & identical to R7's placement, epilogue
// element-mapping identical to R7's Os round trip, reg structure = R7).
// R11 -> R12: back to the R7 operating point (best measured: 51.8us), which
// R8-R11 showed is a sharp local optimum in occupancy x registers x weight
// redundancy (MT=64, 512x512, 2 WGs/CU staggered, 2-frag N-slices, ring-2,
// 64 VGPR + 64 AGPR exactly). Changes vs R7, only validated/zero-cost levers:
//  * Direct-store epilogue (validated in R10): oacc + b2-wsum + residual ->
//    float4 global stores. Removes the 69.6KB O-tile LDS round-trip and its
//    2 barriers; pool shrinks to Xs+Hs = 67.6KB (still 2 WGs/CU).
//  * T5 s_setprio(1) around both MFMA kc-loops: the two independently-phased
//    WGs/CU give the CU scheduler wave-role diversity (one WG in MFMA while
//    the other stages/stores); setprio costs 0 registers.
//  * Coalesced prepack (since R8).

#define C_DIM 256
#define S_DIM 16384          // T*H*W
#define E_DIM 4
#define MT 64                // positions per workgroup
#define XST 264              // Xs/Hs row stride in shorts (16B-aligned rows)
#define WFRAG_ELEMS 262144   // elements per prepacked weight tensor (4*16*8*64*8)

typedef __attribute__((ext_vector_type(8))) short bf16x8;
typedef __attribute__((ext_vector_type(4))) float f32x4;

__device__ __forceinline__ short bfq(float f) {
  __hip_bfloat16 h = __float2bfloat16(f);
  return *(short*)&h;
}

// Prepack: dst[(half,e,nt,kc,lane,j)] = src[(e*256 + nt*16 + (lane&15))*256
//                                           + kc*32 + (lane>>4)*8 + j]
// B-operand fragment layout for mfma_f32_16x16x32_bf16: n=lane&15, k=(lane>>4)*8+j.
// 32 consecutive threads read one contiguous 1KB source row (fully coalesced);
// the 16B fragment stores scatter (fire-and-forget).
__global__ __launch_bounds__(256) void prepack_kernel(
    const float* __restrict__ w1, const float* __restrict__ w2,
    __hip_bfloat16* __restrict__ dst)
{
  int o8   = blockIdx.x * 256 + threadIdx.x;  // 0 .. 65535 (8-elem chunks)
  int half = o8 >> 15;                        // 0: w1, 1: w2
  int idx  = o8 & 32767;
  int j    = idx & 31;                        // 8-float chunk within source row
  int rowid= idx >> 5;                        // e*256 + nt*16 + row, 0..1023
  int e    = rowid >> 8;
  int nt   = (rowid >> 4) & 15;
  int row  = rowid & 15;
  int kc   = j >> 2;
  int col8 = j & 3;
  int lane = (col8 << 4) | row;
  const float* src = half ? w2 : w1;
  const float* s = src + rowid * 256 + j * 8;
  const float4 v0 = *(const float4*)s;
  const float4 v1 = *(const float4*)(s + 4);
  bf16x8 outv = {bfq(v0.x), bfq(v0.y), bfq(v0.z), bfq(v0.w),
                 bfq(v1.x), bfq(v1.y), bfq(v1.z), bfq(v1.w)};
  int chunk = ((e*16 + nt)*8 + kc)*64 + lane;
  *(bf16x8*)((short*)dst + half*WFRAG_ELEMS + chunk*8) = outv;
}

// GEMM1 over MTC gathered M-tiles; barrier (protecting Hs readers of the
// previous expert's GEMM2) sits BETWEEN the MFMA loop and the H-scatter.
// Ring-2 weight prefetch; setprio(1) across the MFMA cluster (T5).
template<int MTC>
__device__ __forceinline__ void gemm1_sparse(
    const short* XsS, short* HsS, const short* w1e, const float* b1e,
    const unsigned char* plist_e, const float* wgtg_e,
    int wv, int r, int q, bool dosync)
{
  f32x4 hacc[MTC][2];
#pragma unroll
  for (int i = 0; i < MTC; ++i)
#pragma unroll
    for (int j = 0; j < 2; ++j) hacc[i][j] = (f32x4){0.f, 0.f, 0.f, 0.f};

  int aoff[MTC];
#pragma unroll
  for (int Mt = 0; Mt < MTC; ++Mt)
    aoff[Mt] = (int)plist_e[Mt*16 + r] * XST;

  bf16x8 bw[2][2];
#pragma unroll
  for (int t = 0; t < 2; ++t) bw[0][t] = *(const bf16x8*)(w1e + (t*8 + 0)*512);
  __builtin_amdgcn_s_setprio(1);
#pragma unroll
  for (int kc = 0; kc < 8; ++kc) {
    if (kc < 7) {
#pragma unroll
      for (int t = 0; t < 2; ++t)
        bw[(kc+1)&1][t] = *(const bf16x8*)(w1e + (t*8 + kc + 1)*512);
    }
    bf16x8 a[MTC];
#pragma unroll
    for (int Mt = 0; Mt < MTC; ++Mt)
      a[Mt] = *(const bf16x8*)(XsS + aoff[Mt] + kc*32 + q*8);
#pragma unroll
    for (int Mt = 0; Mt < MTC; ++Mt)
#pragma unroll
      for (int t = 0; t < 2; ++t)
        hacc[Mt][t] = __builtin_amdgcn_mfma_f32_16x16x32_bf16(a[Mt], bw[kc&1][t], hacc[Mt][t], 0, 0, 0);
  }
  __builtin_amdgcn_s_setprio(0);

  if (dosync) __syncthreads();   // prev expert's GEMM2 done reading Hs

  // epilogue: +b1, fast SiLU, scale by gathered gate weight, scatter to Hs
#pragma unroll
  for (int Mt = 0; Mt < MTC; ++Mt) {
    const int g0 = Mt*16 + q*4;
    const unsigned pw = *(const unsigned*)(plist_e + g0);   // 4 packed positions
    const f32x4 wg = *(const f32x4*)(wgtg_e + g0);
#pragma unroll
    for (int t = 0; t < 2; ++t) {
      const int n = wv*32 + t*16 + r;
      const float bias = b1e[n];
#pragma unroll
      for (int reg = 0; reg < 4; ++reg) {
        const int p = (pw >> (8*reg)) & 255;
        const float z = hacc[Mt][t][reg] + bias;
        const float s = __builtin_amdgcn_rcpf(1.0f + __expf(-z));
        HsS[p*XST + n] = bfq(z * s * wg[reg]);
      }
    }
  }
}

__global__ __launch_bounds__(512, 4) void moe_fused_kernel(
    const float* __restrict__ x,
    const float* __restrict__ gate_w,
    const float* __restrict__ gate_b,
    const float* __restrict__ b1,
    const float* __restrict__ b2,
    const __hip_bfloat16* __restrict__ wp,   // [W1P | W2P] prepacked bf16
    float* __restrict__ out)
{
  // pool (67584 B): Xs (33792) + Hs (33792).
  // Gate fp64 partials (16KB) alias the Hs region before its first use.
  __shared__ __align__(16) char pool[2 * MT * XST * 2];
  __shared__ __align__(16) float Wgt[MT * 4];
  __shared__ __align__(16) unsigned char plist[4][64];  // gathered positions
  __shared__ __align__(16) float WgtG[4][64];           // gathered gate weights
  __shared__ __align__(4)  unsigned char zlist[4][64];  // complement positions
  __shared__ int mcnt[4];

  short* XsS = (short*)pool;
  short* HsS = (short*)(pool + MT * XST * 2);

  const int tid  = threadIdx.x;
  const int lane = tid & 63;
  const int wv   = tid >> 6;     // wave 0..7: owns n-slice [wv*32, wv*32+32)
  const int r    = lane & 15;
  const int q    = lane >> 4;

  const int g  = blockIdx.x;
  const int b  = g >> 8;                 // 256 workgroups per batch
  const int s0 = (g & 255) * MT;
  const float* xb = x + (size_t)b * C_DIM * S_DIM + s0;

  const short* W1P = (const short*)wp;
  const short* W2P = (const short*)wp + WFRAG_ELEMS;

  // ---- FUSED stage X + gate partials: wave wv owns channels [wv*32, wv*32+32),
  //      lane = position. 32 coalesced scalar loads; fp64 gate dot from regs. ----
  {
    const int p  = lane;
    const int c0 = wv * 32;
    float xv[32];
#pragma unroll
    for (int j = 0; j < 32; ++j)
      xv[j] = xb[(size_t)(c0 + j) * S_DIM + p];

    double acc[4] = {0.0, 0.0, 0.0, 0.0};
#pragma unroll
    for (int j = 0; j < 32; ++j) {
      const double xd = (double)xv[j];
      acc[0] += xd * (double)gate_w[0*256 + c0 + j];
      acc[1] += xd * (double)gate_w[1*256 + c0 + j];
      acc[2] += xd * (double)gate_w[2*256 + c0 + j];
      acc[3] += xd * (double)gate_w[3*256 + c0 + j];
    }

#pragma unroll
    for (int k = 0; k < 4; ++k) {
      bf16x8 blk = {bfq(xv[k*8+0]), bfq(xv[k*8+1]), bfq(xv[k*8+2]), bfq(xv[k*8+3]),
                    bfq(xv[k*8+4]), bfq(xv[k*8+5]), bfq(xv[k*8+6]), bfq(xv[k*8+7])};
      *(bf16x8*)(XsS + p*XST + c0 + k*8) = blk;
    }

    double* GateD = (double*)HsS;   // 64pos x 4e x 8grp fp64 = 16KB (alias)
#pragma unroll
    for (int e = 0; e < 4; ++e)
      GateD[(e*8 + wv)*64 + p] = acc[e];
  }
  __syncthreads();   // Xs staged AND gate partials written

  // ---- logits (fp64 reduce, fixed order) + top-2 + softmax, fused via shfl ----
  if (tid < 256) {
    const int p = tid >> 2;
    const int e = tid & 3;
    const double* GateD = (const double*)HsS;
    double s = (double)gate_b[e];
#pragma unroll
    for (int g2 = 0; g2 < 8; ++g2) s += GateD[(e*8 + g2)*64 + p];
    const float la = (float)s;              // l[e]
    const float lb = __shfl_xor(la, 1, 64); // l[e^1]
    const float lc = __shfl_xor(la, 2, 64); // l[e^2]
    const float ld = __shfl_xor(lb, 2, 64); // l[e^3]
    if (e == 0) {
      const float l0 = la, l1 = lb, l2 = lc, l3 = ld;
      int i1 = 0; float v1 = l0;
      if (l1 > v1) { v1 = l1; i1 = 1; }
      if (l2 > v1) { v1 = l2; i1 = 2; }
      if (l3 > v1) { v1 = l3; i1 = 3; }
      float v2 = -3.0e38f; int i2 = 0;
      if (i1 != 0 && l0 > v2) { v2 = l0; i2 = 0; }
      if (i1 != 1 && l1 > v2) { v2 = l1; i2 = 1; }
      if (i1 != 2 && l2 > v2) { v2 = l2; i2 = 2; }
      if (i1 != 3 && l3 > v2) { v2 = l3; i2 = 3; }
      const float wA = 1.0f / (1.0f + __expf(v2 - v1));
      const float wB = 1.0f - wA;
      f32x4 w;
      w[0] = (i1 == 0) ? wA : ((i2 == 0) ? wB : 0.0f);
      w[1] = (i1 == 1) ? wA : ((i2 == 1) ? wB : 0.0f);
      w[2] = (i1 == 2) ? wA : ((i2 == 2) ? wB : 0.0f);
      w[3] = (i1 == 3) ? wA : ((i2 == 3) ? wB : 0.0f);
      *(f32x4*)(&Wgt[p*4]) = w;
    }
  }
  __syncthreads();   // Wgt final

  // ---- per-expert gather lists via ballot (waves 0..3) ----
  if (wv < 4) {
    const int e = wv;
    const int p = lane;
    const float w = Wgt[p*4 + e];
    const bool sel = (w != 0.0f);
    const unsigned long long mask = __ballot(sel);
    const int below = __popcll(mask & ((1ull << p) - 1ull));
    const int m = __popcll(mask);
    const int pad = (((m + 15) >> 4) << 4) - m;
    if (sel) {
      plist[e][below] = (unsigned char)p;
      WgtG[e][below]  = w;
    } else {
      const int zidx = p - below;
      zlist[e][zidx] = (unsigned char)p;
      if (zidx < pad) {   // tail-tile padding: weight-0 complement rows
        plist[e][m + zidx] = (unsigned char)p;
        WgtG[e][m + zidx]  = 0.0f;
      }
    }
    if (p == 0) mcnt[e] = m;
  }
  __syncthreads();   // lists final (also: GateD fully consumed before H-scatter)

  f32x4 oacc[4][2];   // [Mt][t]: persistent out accumulator, K=1024 concat
#pragma unroll
  for (int i = 0; i < 4; ++i)
#pragma unroll
    for (int j = 0; j < 2; ++j) oacc[i][j] = (f32x4){0.f, 0.f, 0.f, 0.f};

  for (int e = 0; e < E_DIM; ++e) {
    const int me = mcnt[e];   // WG-uniform
    const int mt = __builtin_amdgcn_readfirstlane((me + 15) >> 4);
    const short* w1e = W1P + ((e*16 + wv*2)*8)*512 + lane*8;
    const float* b1e = b1 + e*256;
    const bool dosync = (e > 0);   // wait for prev GEMM2's Hs readers

    if      (mt == 2) gemm1_sparse<2>(XsS, HsS, w1e, b1e, plist[e], WgtG[e], wv, r, q, dosync);
    else if (mt == 3) gemm1_sparse<3>(XsS, HsS, w1e, b1e, plist[e], WgtG[e], wv, r, q, dosync);
    else if (mt == 4) gemm1_sparse<4>(XsS, HsS, w1e, b1e, plist[e], WgtG[e], wv, r, q, dosync);
    else if (mt == 1) gemm1_sparse<1>(XsS, HsS, w1e, b1e, plist[e], WgtG[e], wv, r, q, dosync);
    else { if (dosync) __syncthreads(); }   // mt==0: still must sync

    // GEMM2 prologue: first kc B-fragments, issued before zero-fill + barrier
    const short* w2e = W2P + ((e*16 + wv*2)*8)*512 + lane*8;
    bf16x8 cw[2][2];
#pragma unroll
    for (int t = 0; t < 2; ++t) cw[0][t] = *(const bf16x8*)(w2e + (t*8 + 0)*512);

    // zero-fill complement rows of Hs (positions not using expert e)
    {
      const int zm = MT - me;
      const bf16x8 zz = {0,0,0,0,0,0,0,0};
      for (int i = tid; i < zm*32; i += 512) {
        const int row = zlist[e][i >> 5];
        *(bf16x8*)(HsS + row*XST + (i & 31)*8) = zz;
      }
    }
    __syncthreads();   // Hs complete (gathered writes + zero fill)

    // ---- GEMM2: oacc += H_e(64x256) @ W2_e^T slice, ring-2 prefetch ----
    {
      __builtin_amdgcn_s_setprio(1);
#pragma unroll
      for (int kc = 0; kc < 8; ++kc) {
        if (kc < 7) {
#pragma unroll
          for (int t = 0; t < 2; ++t)
            cw[(kc+1)&1][t] = *(const bf16x8*)(w2e + (t*8 + kc + 1)*512);
        }
        bf16x8 a[4];
#pragma unroll
        for (int Mt = 0; Mt < 4; ++Mt)
          a[Mt] = *(const bf16x8*)(HsS + (Mt*16 + r)*XST + kc*32 + q*8);
#pragma unroll
        for (int Mt = 0; Mt < 4; ++Mt)
#pragma unroll
          for (int t = 0; t < 2; ++t)
            oacc[Mt][t] = __builtin_amdgcn_mfma_f32_16x16x32_bf16(a[Mt], cw[kc&1][t], oacc[Mt][t], 0, 0, 0);
      }
      __builtin_amdgcn_s_setprio(0);
    }
    // no barrier here: next expert's GEMM1 compute doesn't touch Hs; the
    // barrier protecting Hs sits inside gemm1_sparse, before its scatter.
  }

  // ---- O epilogue: direct stores (validated in R10). Lane holds 4
  //      CONSECUTIVE positions per fragment (D row = q*4+reg): float4
  //      res/store per (Mt,t). Reads Wgt (stable LDS) + regs: no barrier. ----
  {
    float b2v[2][4];   // [t][e] for c = wv*32 + t*16 + r
#pragma unroll
    for (int t = 0; t < 2; ++t) {
      const int c = wv*32 + t*16 + r;
#pragma unroll
      for (int e = 0; e < 4; ++e) b2v[t][e] = b2[e*256 + c];
    }
    float* ob = out + (size_t)b * C_DIM * S_DIM + s0;
#pragma unroll
    for (int Mt = 0; Mt < 4; ++Mt) {
      const int pb = Mt*16 + q*4;
      f32x4 wv4[4];
#pragma unroll
      for (int reg = 0; reg < 4; ++reg)
        wv4[reg] = *(const f32x4*)(&Wgt[(pb + reg)*4]);
#pragma unroll
      for (int t = 0; t < 2; ++t) {
        const int c = wv*32 + t*16 + r;
        f32x4 v = oacc[Mt][t];
#pragma unroll
        for (int reg = 0; reg < 4; ++reg)
          v[reg] += wv4[reg][0]*b2v[t][0] + wv4[reg][1]*b2v[t][1]
                  + wv4[reg][2]*b2v[t][2] + wv4[reg][3]*b2v[t][3];
        const float4 xr = *(const float4*)(xb + (size_t)c*S_DIM + pb);
        float4 res;
        res.x = v[0] + xr.x; res.y = v[1] + xr.y;
        res.z = v[2] + xr.z; res.w = v[3] + xr.w;
        *(float4*)(ob + (size_t)c*S_DIM + pb) = res;
      }
    }
  }
}

extern "C" void kernel_launch(void* const* d_in, const int* in_sizes, int n_in,
                              void* d_out, int out_size, void* d_ws, size_t ws_size,
                              hipStream_t stream)
{
  (void)in_sizes; (void)n_in; (void)out_size; (void)ws_size;
  const float* x      = (const float*)d_in[0];
  const float* gate_w = (const float*)d_in[1];
  const float* gate_b = (const float*)d_in[2];
  const float* w1     = (const float*)d_in[3];
  const float* b1     = (const float*)d_in[4];
  const float* w2     = (const float*)d_in[5];
  const float* b2     = (const float*)d_in[6];
  float* out = (float*)d_out;
  __hip_bfloat16* wpack = (__hip_bfloat16*)d_ws;   // needs 1 MiB of scratch

  prepack_kernel<<<256, 256, 0, stream>>>(w1, w2, wpack);
  moe_fused_kernel<<<512, 512, 0, stream>>>(x, gate_w, gate_b, b1, b2, wpack, out);
}

// Round 8
// 127.925 us; speedup vs baseline: 1.1471x; 1.0057x over previous
//
#include <hip/hip_runtime.h>
#include <hip/hip_bf16.h>

// MoE fused block, MI355X gfx950.
// Shapes: B=2, C=256, T*H*W=16384, E=4, K=2. All inputs fp32, output fp32.
//
// R12 -> R13: R12 measured == R7 (51.9us): epilogue/setprio were not on the
// critical path -> the stall is load latency inside the kc chains. Targeted
// fix with a register audit (R9 lesson: both-GEMM deep rings + cross-staging
// prologue hoists spill; GEMM2 alone has headroom since hacc is dead there):
//  * GEMM2 weight ring 2 -> 4 (depth-3): prologue preloads kc=0..2 before the
//    zero-fill barrier (latency absorbed into the barrier's vmcnt drain);
//    steady state loads kc+3 ahead of kc's MFMA cluster (~3 kc of cover vs
//    contended L2 latency). GEMM2-phase regs: cw 32 + a 16 + addr ~10 arch,
//    acc 32 -> ~90/128. GEMM1 phase unchanged (44 arch + 64 acc = 108).
//  * Everything else byte-identical to R12 (MT=64, 512x512, 2 WGs/CU,
//    direct-store epilogue, setprio, coalesced prepack).

#define C_DIM 256
#define S_DIM 16384          // T*H*W
#define E_DIM 4
#define MT 64                // positions per workgroup
#define XST 264              // Xs/Hs row stride in shorts (16B-aligned rows)
#define WFRAG_ELEMS 262144   // elements per prepacked weight tensor (4*16*8*64*8)

typedef __attribute__((ext_vector_type(8))) short bf16x8;
typedef __attribute__((ext_vector_type(4))) float f32x4;

__device__ __forceinline__ short bfq(float f) {
  __hip_bfloat16 h = __float2bfloat16(f);
  return *(short*)&h;
}

// Prepack: dst[(half,e,nt,kc,lane,j)] = src[(e*256 + nt*16 + (lane&15))*256
//                                           + kc*32 + (lane>>4)*8 + j]
// B-operand fragment layout for mfma_f32_16x16x32_bf16: n=lane&15, k=(lane>>4)*8+j.
// 32 consecutive threads read one contiguous 1KB source row (fully coalesced);
// the 16B fragment stores scatter (fire-and-forget).
__global__ __launch_bounds__(256) void prepack_kernel(
    const float* __restrict__ w1, const float* __restrict__ w2,
    __hip_bfloat16* __restrict__ dst)
{
  int o8   = blockIdx.x * 256 + threadIdx.x;  // 0 .. 65535 (8-elem chunks)
  int half = o8 >> 15;                        // 0: w1, 1: w2
  int idx  = o8 & 32767;
  int j    = idx & 31;                        // 8-float chunk within source row
  int rowid= idx >> 5;                        // e*256 + nt*16 + row, 0..1023
  int e    = rowid >> 8;
  int nt   = (rowid >> 4) & 15;
  int row  = rowid & 15;
  int kc   = j >> 2;
  int col8 = j & 3;
  int lane = (col8 << 4) | row;
  const float* src = half ? w2 : w1;
  const float* s = src + rowid * 256 + j * 8;
  const float4 v0 = *(const float4*)s;
  const float4 v1 = *(const float4*)(s + 4);
  bf16x8 outv = {bfq(v0.x), bfq(v0.y), bfq(v0.z), bfq(v0.w),
                 bfq(v1.x), bfq(v1.y), bfq(v1.z), bfq(v1.w)};
  int chunk = ((e*16 + nt)*8 + kc)*64 + lane;
  *(bf16x8*)((short*)dst + half*WFRAG_ELEMS + chunk*8) = outv;
}

// GEMM1 over MTC gathered M-tiles; barrier (protecting Hs readers of the
// previous expert's GEMM2) sits BETWEEN the MFMA loop and the H-scatter.
// Ring-2 weight prefetch; setprio(1) across the MFMA cluster (T5).
template<int MTC>
__device__ __forceinline__ void gemm1_sparse(
    const short* XsS, short* HsS, const short* w1e, const float* b1e,
    const unsigned char* plist_e, const float* wgtg_e,
    int wv, int r, int q, bool dosync)
{
  f32x4 hacc[MTC][2];
#pragma unroll
  for (int i = 0; i < MTC; ++i)
#pragma unroll
    for (int j = 0; j < 2; ++j) hacc[i][j] = (f32x4){0.f, 0.f, 0.f, 0.f};

  int aoff[MTC];
#pragma unroll
  for (int Mt = 0; Mt < MTC; ++Mt)
    aoff[Mt] = (int)plist_e[Mt*16 + r] * XST;

  bf16x8 bw[2][2];
#pragma unroll
  for (int t = 0; t < 2; ++t) bw[0][t] = *(const bf16x8*)(w1e + (t*8 + 0)*512);
  __builtin_amdgcn_s_setprio(1);
#pragma unroll
  for (int kc = 0; kc < 8; ++kc) {
    if (kc < 7) {
#pragma unroll
      for (int t = 0; t < 2; ++t)
        bw[(kc+1)&1][t] = *(const bf16x8*)(w1e + (t*8 + kc + 1)*512);
    }
    bf16x8 a[MTC];
#pragma unroll
    for (int Mt = 0; Mt < MTC; ++Mt)
      a[Mt] = *(const bf16x8*)(XsS + aoff[Mt] + kc*32 + q*8);
#pragma unroll
    for (int Mt = 0; Mt < MTC; ++Mt)
#pragma unroll
      for (int t = 0; t < 2; ++t)
        hacc[Mt][t] = __builtin_amdgcn_mfma_f32_16x16x32_bf16(a[Mt], bw[kc&1][t], hacc[Mt][t], 0, 0, 0);
  }
  __builtin_amdgcn_s_setprio(0);

  if (dosync) __syncthreads();   // prev expert's GEMM2 done reading Hs

  // epilogue: +b1, fast SiLU, scale by gathered gate weight, scatter to Hs
#pragma unroll
  for (int Mt = 0; Mt < MTC; ++Mt) {
    const int g0 = Mt*16 + q*4;
    const unsigned pw = *(const unsigned*)(plist_e + g0);   // 4 packed positions
    const f32x4 wg = *(const f32x4*)(wgtg_e + g0);
#pragma unroll
    for (int t = 0; t < 2; ++t) {
      const int n = wv*32 + t*16 + r;
      const float bias = b1e[n];
#pragma unroll
      for (int reg = 0; reg < 4; ++reg) {
        const int p = (pw >> (8*reg)) & 255;
        const float z = hacc[Mt][t][reg] + bias;
        const float s = __builtin_amdgcn_rcpf(1.0f + __expf(-z));
        HsS[p*XST + n] = bfq(z * s * wg[reg]);
      }
    }
  }
}

__global__ __launch_bounds__(512, 4) void moe_fused_kernel(
    const float* __restrict__ x,
    const float* __restrict__ gate_w,
    const float* __restrict__ gate_b,
    const float* __restrict__ b1,
    const float* __restrict__ b2,
    const __hip_bfloat16* __restrict__ wp,   // [W1P | W2P] prepacked bf16
    float* __restrict__ out)
{
  // pool (67584 B): Xs (33792) + Hs (33792).
  // Gate fp64 partials (16KB) alias the Hs region before its first use.
  __shared__ __align__(16) char pool[2 * MT * XST * 2];
  __shared__ __align__(16) float Wgt[MT * 4];
  __shared__ __align__(16) unsigned char plist[4][64];  // gathered positions
  __shared__ __align__(16) float WgtG[4][64];           // gathered gate weights
  __shared__ __align__(4)  unsigned char zlist[4][64];  // complement positions
  __shared__ int mcnt[4];

  short* XsS = (short*)pool;
  short* HsS = (short*)(pool + MT * XST * 2);

  const int tid  = threadIdx.x;
  const int lane = tid & 63;
  const int wv   = tid >> 6;     // wave 0..7: owns n-slice [wv*32, wv*32+32)
  const int r    = lane & 15;
  const int q    = lane >> 4;

  const int g  = blockIdx.x;
  const int b  = g >> 8;                 // 256 workgroups per batch
  const int s0 = (g & 255) * MT;
  const float* xb = x + (size_t)b * C_DIM * S_DIM + s0;

  const short* W1P = (const short*)wp;
  const short* W2P = (const short*)wp + WFRAG_ELEMS;

  // ---- FUSED stage X + gate partials: wave wv owns channels [wv*32, wv*32+32),
  //      lane = position. 32 coalesced scalar loads; fp64 gate dot from regs. ----
  {
    const int p  = lane;
    const int c0 = wv * 32;
    float xv[32];
#pragma unroll
    for (int j = 0; j < 32; ++j)
      xv[j] = xb[(size_t)(c0 + j) * S_DIM + p];

    double acc[4] = {0.0, 0.0, 0.0, 0.0};
#pragma unroll
    for (int j = 0; j < 32; ++j) {
      const double xd = (double)xv[j];
      acc[0] += xd * (double)gate_w[0*256 + c0 + j];
      acc[1] += xd * (double)gate_w[1*256 + c0 + j];
      acc[2] += xd * (double)gate_w[2*256 + c0 + j];
      acc[3] += xd * (double)gate_w[3*256 + c0 + j];
    }

#pragma unroll
    for (int k = 0; k < 4; ++k) {
      bf16x8 blk = {bfq(xv[k*8+0]), bfq(xv[k*8+1]), bfq(xv[k*8+2]), bfq(xv[k*8+3]),
                    bfq(xv[k*8+4]), bfq(xv[k*8+5]), bfq(xv[k*8+6]), bfq(xv[k*8+7])};
      *(bf16x8*)(XsS + p*XST + c0 + k*8) = blk;
    }

    double* GateD = (double*)HsS;   // 64pos x 4e x 8grp fp64 = 16KB (alias)
#pragma unroll
    for (int e = 0; e < 4; ++e)
      GateD[(e*8 + wv)*64 + p] = acc[e];
  }
  __syncthreads();   // Xs staged AND gate partials written

  // ---- logits (fp64 reduce, fixed order) + top-2 + softmax, fused via shfl ----
  if (tid < 256) {
    const int p = tid >> 2;
    const int e = tid & 3;
    const double* GateD = (const double*)HsS;
    double s = (double)gate_b[e];
#pragma unroll
    for (int g2 = 0; g2 < 8; ++g2) s += GateD[(e*8 + g2)*64 + p];
    const float la = (float)s;              // l[e]
    const float lb = __shfl_xor(la, 1, 64); // l[e^1]
    const float lc = __shfl_xor(la, 2, 64); // l[e^2]
    const float ld = __shfl_xor(lb, 2, 64); // l[e^3]
    if (e == 0) {
      const float l0 = la, l1 = lb, l2 = lc, l3 = ld;
      int i1 = 0; float v1 = l0;
      if (l1 > v1) { v1 = l1; i1 = 1; }
      if (l2 > v1) { v1 = l2; i1 = 2; }
      if (l3 > v1) { v1 = l3; i1 = 3; }
      float v2 = -3.0e38f; int i2 = 0;
      if (i1 != 0 && l0 > v2) { v2 = l0; i2 = 0; }
      if (i1 != 1 && l1 > v2) { v2 = l1; i2 = 1; }
      if (i1 != 2 && l2 > v2) { v2 = l2; i2 = 2; }
      if (i1 != 3 && l3 > v2) { v2 = l3; i2 = 3; }
      const float wA = 1.0f / (1.0f + __expf(v2 - v1));
      const float wB = 1.0f - wA;
      f32x4 w;
      w[0] = (i1 == 0) ? wA : ((i2 == 0) ? wB : 0.0f);
      w[1] = (i1 == 1) ? wA : ((i2 == 1) ? wB : 0.0f);
      w[2] = (i1 == 2) ? wA : ((i2 == 2) ? wB : 0.0f);
      w[3] = (i1 == 3) ? wA : ((i2 == 3) ? wB : 0.0f);
      *(f32x4*)(&Wgt[p*4]) = w;
    }
  }
  __syncthreads();   // Wgt final

  // ---- per-expert gather lists via ballot (waves 0..3) ----
  if (wv < 4) {
    const int e = wv;
    const int p = lane;
    const float w = Wgt[p*4 + e];
    const bool sel = (w != 0.0f);
    const unsigned long long mask = __ballot(sel);
    const int below = __popcll(mask & ((1ull << p) - 1ull));
    const int m = __popcll(mask);
    const int pad = (((m + 15) >> 4) << 4) - m;
    if (sel) {
      plist[e][below] = (unsigned char)p;
      WgtG[e][below]  = w;
    } else {
      const int zidx = p - below;
      zlist[e][zidx] = (unsigned char)p;
      if (zidx < pad) {   // tail-tile padding: weight-0 complement rows
        plist[e][m + zidx] = (unsigned char)p;
        WgtG[e][m + zidx]  = 0.0f;
      }
    }
    if (p == 0) mcnt[e] = m;
  }
  __syncthreads();   // lists final (also: GateD fully consumed before H-scatter)

  f32x4 oacc[4][2];   // [Mt][t]: persistent out accumulator, K=1024 concat
#pragma unroll
  for (int i = 0; i < 4; ++i)
#pragma unroll
    for (int j = 0; j < 2; ++j) oacc[i][j] = (f32x4){0.f, 0.f, 0.f, 0.f};

  for (int e = 0; e < E_DIM; ++e) {
    const int me = mcnt[e];   // WG-uniform
    const int mt = __builtin_amdgcn_readfirstlane((me + 15) >> 4);
    const short* w1e = W1P + ((e*16 + wv*2)*8)*512 + lane*8;
    const float* b1e = b1 + e*256;
    const bool dosync = (e > 0);   // wait for prev GEMM2's Hs readers

    if      (mt == 2) gemm1_sparse<2>(XsS, HsS, w1e, b1e, plist[e], WgtG[e], wv, r, q, dosync);
    else if (mt == 3) gemm1_sparse<3>(XsS, HsS, w1e, b1e, plist[e], WgtG[e], wv, r, q, dosync);
    else if (mt == 4) gemm1_sparse<4>(XsS, HsS, w1e, b1e, plist[e], WgtG[e], wv, r, q, dosync);
    else if (mt == 1) gemm1_sparse<1>(XsS, HsS, w1e, b1e, plist[e], WgtG[e], wv, r, q, dosync);
    else { if (dosync) __syncthreads(); }   // mt==0: still must sync

    // GEMM2 prologue: kc=0..2 B-fragment pairs issued before zero-fill +
    // barrier -- their latency is absorbed into the barrier's vmcnt drain.
    const short* w2e = W2P + ((e*16 + wv*2)*8)*512 + lane*8;
    bf16x8 cw[4][2];
#pragma unroll
    for (int kk = 0; kk < 3; ++kk)
#pragma unroll
      for (int t = 0; t < 2; ++t)
        cw[kk][t] = *(const bf16x8*)(w2e + (t*8 + kk)*512);

    // zero-fill complement rows of Hs (positions not using expert e)
    {
      const int zm = MT - me;
      const bf16x8 zz = {0,0,0,0,0,0,0,0};
      for (int i = tid; i < zm*32; i += 512) {
        const int row = zlist[e][i >> 5];
        *(bf16x8*)(HsS + row*XST + (i & 31)*8) = zz;
      }
    }
    __syncthreads();   // Hs complete (gathered writes + zero fill)

    // ---- GEMM2: oacc += H_e(64x256) @ W2_e^T slice, ring-4 depth-3 ----
    {
      __builtin_amdgcn_s_setprio(1);
#pragma unroll
      for (int kc = 0; kc < 8; ++kc) {
        if (kc < 5) {   // load kc+3 into slot (kc+3)&3 (!= kc&3: safe)
#pragma unroll
          for (int t = 0; t < 2; ++t)
            cw[(kc+3)&3][t] = *(const bf16x8*)(w2e + (t*8 + kc + 3)*512);
        }
        bf16x8 a[4];
#pragma unroll
        for (int Mt = 0; Mt < 4; ++Mt)
          a[Mt] = *(const bf16x8*)(HsS + (Mt*16 + r)*XST + kc*32 + q*8);
#pragma unroll
        for (int Mt = 0; Mt < 4; ++Mt)
#pragma unroll
          for (int t = 0; t < 2; ++t)
            oacc[Mt][t] = __builtin_amdgcn_mfma_f32_16x16x32_bf16(a[Mt], cw[kc&3][t], oacc[Mt][t], 0, 0, 0);
      }
      __builtin_amdgcn_s_setprio(0);
    }
    // no barrier here: next expert's GEMM1 compute doesn't touch Hs; the
    // barrier protecting Hs sits inside gemm1_sparse, before its scatter.
  }

  // ---- O epilogue: direct stores (validated in R10). Lane holds 4
  //      CONSECUTIVE positions per fragment (D row = q*4+reg): float4
  //      res/store per (Mt,t). Reads Wgt (stable LDS) + regs: no barrier. ----
  {
    float b2v[2][4];   // [t][e] for c = wv*32 + t*16 + r
#pragma unroll
    for (int t = 0; t < 2; ++t) {
      const int c = wv*32 + t*16 + r;
#pragma unroll
      for (int e = 0; e < 4; ++e) b2v[t][e] = b2[e*256 + c];
    }
    float* ob = out + (size_t)b * C_DIM * S_DIM + s0;
#pragma unroll
    for (int Mt = 0; Mt < 4; ++Mt) {
      const int pb = Mt*16 + q*4;
      f32x4 wv4[4];
#pragma unroll
      for (int reg = 0; reg < 4; ++reg)
        wv4[reg] = *(const f32x4*)(&Wgt[(pb + reg)*4]);
#pragma unroll
      for (int t = 0; t < 2; ++t) {
        const int c = wv*32 + t*16 + r;
        f32x4 v = oacc[Mt][t];
#pragma unroll
        for (int reg = 0; reg < 4; ++reg)
          v[reg] += wv4[reg][0]*b2v[t][0] + wv4[reg][1]*b2v[t][1]
                  + wv4[reg][2]*b2v[t][2] + wv4[reg][3]*b2v[t][3];
        const float4 xr = *(const float4*)(xb + (size_t)c*S_DIM + pb);
        float4 res;
        res.x = v[0] + xr.x; res.y = v[1] + xr.y;
        res.z = v[2] + xr.z; res.w = v[3] + xr.w;
        *(float4*)(ob + (size_t)c*S_DIM + pb) = res;
      }
    }
  }
}

extern "C" void kernel_launch(void* const* d_in, const int* in_sizes, int n_in,
                              void* d_out, int out_size, void* d_ws, size_t ws_size,
                              hipStream_t stream)
{
  (void)in_sizes; (void)n_in; (void)out_size; (void)ws_size;
  const float* x      = (const float*)d_in[0];
  const float* gate_w = (const float*)d_in[1];
  const float* gate_b = (const float*)d_in[2];
  const float* w1     = (const float*)d_in[3];
  const float* b1     = (const float*)d_in[4];
  const float* w2     = (const float*)d_in[5];
  const float* b2     = (const float*)d_in[6];
  float* out = (float*)d_out;
  __hip_bfloat16* wpack = (__hip_bfloat16*)d_ws;   // needs 1 MiB of scratch

  prepack_kernel<<<256, 256, 0, stream>>>(w1, w2, wpack);
  moe_fused_kernel<<<512, 512, 0, stream>>>(x, gate_w, gate_b, b1, b2, wpack, out);
}